// Round 9
// baseline (302.019 us; speedup 1.0000x reference)
//
#include <hip/hip_runtime.h>
#include <hip/hip_bf16.h>

typedef __attribute__((ext_vector_type(8))) __bf16 bf16x8;
typedef __attribute__((ext_vector_type(4))) __bf16 bf16x4;
typedef __attribute__((ext_vector_type(2))) __bf16 bf16x2;
typedef __attribute__((ext_vector_type(4))) float f32x4;
typedef __attribute__((ext_vector_type(4))) unsigned u32x4;

#define MFMA(a, b, c) __builtin_amdgcn_mfma_f32_16x16x32_bf16((a), (b), (c), 0, 0, 0)

__device__ __forceinline__ bf16x8 pack8(f32x4 a, f32x4 b) {
    bf16x8 r;
    r[0] = (__bf16)a[0]; r[1] = (__bf16)a[1]; r[2] = (__bf16)a[2]; r[3] = (__bf16)a[3];
    r[4] = (__bf16)b[0]; r[5] = (__bf16)b[1]; r[6] = (__bf16)b[2]; r[7] = (__bf16)b[3];
    return r;
}

__device__ __forceinline__ bf16x8 cvt8(const float* __restrict__ p) {
    return pack8(*(const f32x4*)(p), *(const f32x4*)(p + 4));
}

// pack relu(a),relu(b) into one u32 of 2 bf16
__device__ __forceinline__ unsigned pkrelu(float a, float b) {
    unsigned short ua = __builtin_bit_cast(unsigned short, (__bf16)fmaxf(a, 0.f));
    unsigned short ub = __builtin_bit_cast(unsigned short, (__bf16)fmaxf(b, 0.f));
    return (unsigned)ua | ((unsigned)ub << 16);
}

// Cross-lane transpose of the transposed-layer-1 output into the next layer's
// B fragments.  acc[nt][r] = h[entity l15][col nt*16 + l4*4 + r] (relu applied
// here).  Result: bfr[j] = h[entity l15][j*32 + l4*8 .. +7].
// Exchange is among the 4 lanes sharing l15 (verified index map).
__device__ __forceinline__ void transpose_h(const f32x4* acc, bf16x8* bfr,
                                            int l15, int l4) {
    unsigned pk[4][2];
#pragma unroll
    for (int nt = 0; nt < 4; ++nt) {
        pk[nt][0] = pkrelu(acc[nt][0], acc[nt][1]);
        pk[nt][1] = pkrelu(acc[nt][2], acc[nt][3]);
    }
    const int srcA = l15 + 16 * ((2 * l4) & 3);
    const int srcB = l15 + 16 * ((2 * l4 + 1) & 3);
    const bool hi = (l4 >> 1) != 0;
#pragma unroll
    for (int j = 0; j < 2; ++j) {
        unsigned a0 = __shfl(pk[j * 2][0], srcA), a1 = __shfl(pk[j * 2][1], srcA);
        unsigned c0 = __shfl(pk[j * 2 + 1][0], srcA), c1 = __shfl(pk[j * 2 + 1][1], srcA);
        unsigned b0 = __shfl(pk[j * 2][0], srcB), b1 = __shfl(pk[j * 2][1], srcB);
        unsigned d0 = __shfl(pk[j * 2 + 1][0], srcB), d1 = __shfl(pk[j * 2 + 1][1], srcB);
        u32x4 uv;
        uv[0] = hi ? c0 : a0; uv[1] = hi ? c1 : a1;
        uv[2] = hi ? d0 : b0; uv[3] = hi ? d1 : b1;
        bfr[j] = __builtin_bit_cast(bf16x8, uv);
    }
}

// ---------------------------------------------------------------------------
// tiny zero kernel (hipMemsetAsync graph-captures into a 119us fillBuffer)
// ---------------------------------------------------------------------------
__global__ __launch_bounds__(256) void zero_i32(int* __restrict__ p, int n) {
    for (int i = blockIdx.x * blockDim.x + threadIdx.x; i < n;
         i += gridDim.x * blockDim.x)
        p[i] = 0;
}

// ---------------------------------------------------------------------------
// Kernel 1 (transposed): y1f = bf16 fragment-permuted (col' = l4*16+nt*4+r of
// x @ W1a[0:128,:] + b1a);  y2 = f32 x @ W2a[0:128,:] + b2a
// ---------------------------------------------------------------------------
__global__ __launch_bounds__(256) void precompute_y(
    const float* __restrict__ x,
    const float* __restrict__ W1a, const float* __restrict__ b1a,
    const float* __restrict__ W2a, const float* __restrict__ b2a,
    __bf16* __restrict__ y1f, float* __restrict__ y2,
    int N, int ntiles)
{
    const int LDK = 136;                       // 128 + 8 pad
    __shared__ __align__(16) __bf16 w1t[64 * 136];
    __shared__ __align__(16) __bf16 w2t[64 * 136];
    for (int idx = threadIdx.x; idx < 64 * 128; idx += 256) {
        int k = idx >> 6, n = idx & 63;
        w1t[n * LDK + k] = (__bf16)W1a[k * 64 + n];
        w2t[n * LDK + k] = (__bf16)W2a[k * 64 + n];
    }
    __syncthreads();

    const int lane = threadIdx.x & 63, wave = threadIdx.x >> 6;
    const int l15 = lane & 15, l4 = lane >> 4;

    f32x4 bias1[4], bias2[4];
#pragma unroll
    for (int nt = 0; nt < 4; ++nt) {
        bias1[nt] = *(const f32x4*)(b1a + nt * 16 + l4 * 4);
        bias2[nt] = *(const f32x4*)(b2a + nt * 16 + l4 * 4);
    }

    for (int tile = blockIdx.x * 4 + wave; tile < ntiles; tile += gridDim.x * 4) {
        const int node = tile * 16 + l15;
        const int nrow = min(node, N - 1);
        f32x4 acc1[4], acc2[4];
#pragma unroll
        for (int nt = 0; nt < 4; ++nt) {
            acc1[nt] = (f32x4){0.f, 0.f, 0.f, 0.f};
            acc2[nt] = (f32x4){0.f, 0.f, 0.f, 0.f};
        }
#pragma unroll
        for (int j = 0; j < 4; ++j) {
            const int k0 = j * 32 + l4 * 8;
            bf16x8 b = cvt8(x + (size_t)nrow * 128 + k0);     // B = x^T (lane l15 = node)
#pragma unroll
            for (int nt = 0; nt < 4; ++nt) {
                bf16x8 a1 = *(const bf16x8*)(w1t + (nt * 16 + l15) * LDK + k0);
                acc1[nt] = MFMA(a1, b, acc1[nt]);
                bf16x8 a2 = *(const bf16x8*)(w2t + (nt * 16 + l15) * LDK + k0);
                acc2[nt] = MFMA(a2, b, acc2[nt]);
            }
        }
        if (node < N) {
#pragma unroll
            for (int nt = 0; nt < 4; ++nt) {
                f32x4 v1 = acc1[nt] + bias1[nt];
                bf16x4 bv;
#pragma unroll
                for (int r = 0; r < 4; ++r) bv[r] = (__bf16)v1[r];
                // fragment-permuted: col' = l4*16 + nt*4 + r
                *(bf16x4*)(y1f + (size_t)node * 64 + l4 * 16 + nt * 4) = bv;
                f32x4 v2 = acc2[nt] + bias2[nt];
                *(f32x4*)(y2 + (size_t)node * 64 + nt * 16 + l4 * 4) = v2;
            }
        }
    }
}

// ---------------------------------------------------------------------------
// hist + rank: cnt[rv]++ and rank[e] = arrival order of e within its receiver
// ---------------------------------------------------------------------------
__global__ __launch_bounds__(256) void hist_rank(
    const int* __restrict__ recv, int* __restrict__ cnt,
    int* __restrict__ rank, int E)
{
    for (int e = blockIdx.x * blockDim.x + threadIdx.x; e < E;
         e += gridDim.x * blockDim.x)
        rank[e] = atomicAdd(&cnt[recv[e]], 1);
}

__global__ __launch_bounds__(1024) void scan_offsets(
    const int* __restrict__ cnt, int* __restrict__ offs, int N)
{
    __shared__ int wsum[16];
    __shared__ int stot;
    const int tid = threadIdx.x;
    const int lane = tid & 63, wave = tid >> 6;
    int carry = 0;
    const int CH = 4096;                       // 1024 threads x 4 elems
    for (int base = 0; base < N; base += CH) {
        const int idx = base + tid * 4;
        int v0 = (idx + 0 < N) ? cnt[idx + 0] : 0;
        int v1 = (idx + 1 < N) ? cnt[idx + 1] : 0;
        int v2 = (idx + 2 < N) ? cnt[idx + 2] : 0;
        int v3 = (idx + 3 < N) ? cnt[idx + 3] : 0;
        const int t = v0 + v1 + v2 + v3;
        int s = t;                              // inclusive wave scan
#pragma unroll
        for (int d = 1; d < 64; d <<= 1) {
            int u = __shfl_up(s, d);
            if (lane >= d) s += u;
        }
        if (lane == 63) wsum[wave] = s;
        __syncthreads();
        if (wave == 0) {
            int w = (lane < 16) ? wsum[lane] : 0;
            int ws = w;
#pragma unroll
            for (int d = 1; d < 16; d <<= 1) {
                int u = __shfl_up(ws, d);
                if (lane >= d) ws += u;
            }
            if (lane < 16) wsum[lane] = ws - w;  // exclusive wave offsets
            if (lane == 15) stot = ws;
        }
        __syncthreads();
        const int excl = s - t + wsum[wave] + carry;
        if (idx + 0 < N) offs[idx + 0] = excl;
        if (idx + 1 < N) offs[idx + 1] = excl + v0;
        if (idx + 2 < N) offs[idx + 2] = excl + v0 + v1;
        if (idx + 3 < N) offs[idx + 3] = excl + v0 + v1 + v2;
        carry += stot;
        __syncthreads();                        // protect wsum/stot for next chunk
    }
    if (tid == 0) offs[N] = carry;
}

// ---------------------------------------------------------------------------
// Kernel 2: per-edge MLP.  No atomics (slot p = offs[recv]+rank), no h-LDS
// (shuffle transpose), bf16 fragment-permuted y1 gather (2x16B/lane).
// LDS = weights only (16.6 KB) -> 8 blocks/CU.
// MODE 1 fallback: device fp atomics into agg.
// ---------------------------------------------------------------------------
template<int MODE>
__global__ __launch_bounds__(256) void edge_mlp(
    const float* __restrict__ eattr,
    const int* __restrict__ send, const int* __restrict__ recv,
    const int* __restrict__ rank, const int* __restrict__ offs,
    const float* __restrict__ W1a, const float* __restrict__ W1b,
    const float* __restrict__ b1b,
    const __bf16* __restrict__ y1f,
    __bf16* __restrict__ msgC, float* agg,
    int E, int ntiles)
{
    // fragment-ordered weights: chunk c = k/8, row n, elem i=k%8
    __shared__ __align__(16) __bf16 wfA[8 * 65 * 8];   // W1a[128:192,:]^T
    __shared__ __align__(16) __bf16 wfB[8 * 65 * 8];   // W1b^T
    for (int idx = threadIdx.x; idx < 64 * 64; idx += 256) {
        const int k = idx >> 6, n = idx & 63;
        const int c = k >> 3, i = k & 7;
        wfA[(c * 65 + n) * 8 + i] = (__bf16)W1a[(128 + k) * 64 + n];
        wfB[(c * 65 + n) * 8 + i] = (__bf16)W1b[k * 64 + n];
    }
    __syncthreads();

    const int lane = threadIdx.x & 63, wave = threadIdx.x >> 6;
    const int l15 = lane & 15, l4 = lane >> 4;

    f32x4 biasb[4];
#pragma unroll
    for (int nt = 0; nt < 4; ++nt) biasb[nt] = *(const f32x4*)(b1b + nt * 16 + l4 * 4);

    for (int tile = blockIdx.x * 4 + wave; tile < ntiles; tile += gridDim.x * 4) {
        const int e = tile * 16 + l15;
        const int el = min(e, E - 1);
        const int s = send[el];
        const int rv = recv[el];
        int p = 0;
        if (MODE == 0) p = offs[rv] + rank[el];

        // ---- C-init: y1f gather, 2x16B bf16 (fragment-permuted layout)
        bf16x8 cA = *(const bf16x8*)(y1f + (size_t)s * 64 + l4 * 16);
        bf16x8 cB = *(const bf16x8*)(y1f + (size_t)s * 64 + l4 * 16 + 8);
        f32x4 acc[4];
#pragma unroll
        for (int r = 0; r < 4; ++r) {
            acc[0][r] = (float)cA[r];
            acc[1][r] = (float)cA[4 + r];
            acc[2][r] = (float)cB[r];
            acc[3][r] = (float)cB[4 + r];
        }
        // ---- layer 1 (transposed): A = W1a_e^T frags, B = eattr^T
#pragma unroll
        for (int j = 0; j < 2; ++j) {
            const float* ep = eattr + (size_t)el * 64 + j * 32 + l4 * 8;
            bf16x8 b = pack8(*(const f32x4*)ep, *(const f32x4*)(ep + 4));
            const int c = j * 4 + l4;
#pragma unroll
            for (int nt = 0; nt < 4; ++nt) {
                bf16x8 a = *(const bf16x8*)(wfA + ((c * 65) + nt * 16 + l15) * 8);
                acc[nt] = MFMA(a, b, acc[nt]);
            }
        }
        // ---- relu + transpose to layer-2 B fragments (shuffles, no LDS)
        bf16x8 bfr[2];
        transpose_h(acc, bfr, l15, l4);

        // ---- layer 2 (transposed)
        f32x4 acc2[4];
#pragma unroll
        for (int nt = 0; nt < 4; ++nt) acc2[nt] = biasb[nt];
#pragma unroll
        for (int j = 0; j < 2; ++j) {
            const int c = j * 4 + l4;
#pragma unroll
            for (int nt = 0; nt < 4; ++nt) {
                bf16x8 a = *(const bf16x8*)(wfB + ((c * 65) + nt * 16 + l15) * 8);
                acc2[nt] = MFMA(a, bfr[j], acc2[nt]);
            }
        }
        // ---- emit
        if (e < E) {
            if (MODE == 0) {
                __bf16* row = msgC + (size_t)p * 64;
#pragma unroll
                for (int nt = 0; nt < 4; ++nt) {
                    bf16x4 mv;
#pragma unroll
                    for (int r = 0; r < 4; ++r) mv[r] = (__bf16)fmaxf(acc2[nt][r], 0.f);
                    *(bf16x4*)(row + nt * 16 + l4 * 4) = mv;
                }
            } else {
                float* base = agg + (size_t)rv * 64 + l4 * 4;
#pragma unroll
                for (int nt = 0; nt < 4; ++nt)
#pragma unroll
                    for (int r = 0; r < 4; ++r)
                        unsafeAtomicAdd(base + nt * 16 + r, fmaxf(acc2[nt][r], 0.f));
            }
        }
    }
}

// ---------------------------------------------------------------------------
// Kernel 3 fused: per-wave 16-node tile.
//   (a) streaming reduce of contiguous msgC rows [offs[n],offs[n+1]) -> aggL
//   (b) node MLP: pre = y2 + agg @ W2a[128:192,:]; out = relu(relu(pre)@W2b+b2b)
// ---------------------------------------------------------------------------
__global__ __launch_bounds__(256) void node_fused(
    const unsigned* __restrict__ msg_u,
    const int* __restrict__ offs,
    const float* __restrict__ W2a, const float* __restrict__ W2b,
    const float* __restrict__ b2b,
    const float* __restrict__ y2, float* __restrict__ out,
    int N, int ntiles)
{
    const int LDA = 72;                        // agg row stride (144B, 16B-mult)
    __shared__ __align__(16) __bf16 wfA[8 * 65 * 8];   // W2a[128:192,:]^T
    __shared__ __align__(16) __bf16 wfB[8 * 65 * 8];   // W2b^T
    __shared__ __align__(16) __bf16 aggL[4][16 * 72];
    for (int idx = threadIdx.x; idx < 64 * 64; idx += 256) {
        const int k = idx >> 6, n = idx & 63;
        const int c = k >> 3, i = k & 7;
        wfA[(c * 65 + n) * 8 + i] = (__bf16)W2a[(128 + k) * 64 + n];
        wfB[(c * 65 + n) * 8 + i] = (__bf16)W2b[k * 64 + n];
    }
    __syncthreads();

    const int lane = threadIdx.x & 63, wave = threadIdx.x >> 6;
    const int l15 = lane & 15, l4 = lane >> 4;
    const int half = lane >> 5, cc = lane & 31;
    __bf16* aL = aggL[wave];

    f32x4 biasb[4];
#pragma unroll
    for (int nt = 0; nt < 4; ++nt) biasb[nt] = *(const f32x4*)(b2b + nt * 16 + l4 * 4);

    for (int tile = blockIdx.x * 4 + wave; tile < ntiles; tile += gridDim.x * 4) {
        const int rbase = tile * 16;

        // ---- (a) streaming segment reduce: 2 cols/lane, halves alternate rows
        for (int m = 0; m < 16; ++m) {
            const int node = rbase + m;
            const int oL = offs[min(node, N)], oR = offs[min(node + 1, N)];
            float ax = 0.f, ay = 0.f;
            for (int p = oL + half; p < oR; p += 2) {
                const unsigned u = msg_u[(size_t)p * 32 + cc];
                ax += __uint_as_float(u << 16);
                ay += __uint_as_float(u & 0xffff0000u);
            }
            ax += __shfl_xor(ax, 32);
            ay += __shfl_xor(ay, 32);
            if (half == 0) {
                bf16x2 v; v[0] = (__bf16)ax; v[1] = (__bf16)ay;
                *(bf16x2*)(aL + m * LDA + cc * 2) = v;
            }
        }

        // ---- (b) node MLP (transposed, lane l15 = node row in tile)
        const int node = rbase + l15;
        const int nrow = min(node, N - 1);
        f32x4 acc[4];
#pragma unroll
        for (int nt = 0; nt < 4; ++nt)
            acc[nt] = *(const f32x4*)(y2 + (size_t)nrow * 64 + nt * 16 + l4 * 4);
#pragma unroll
        for (int j = 0; j < 2; ++j) {
            bf16x8 b = *(const bf16x8*)(aL + l15 * LDA + j * 32 + l4 * 8);
            const int c = j * 4 + l4;
#pragma unroll
            for (int nt = 0; nt < 4; ++nt) {
                bf16x8 a = *(const bf16x8*)(wfA + ((c * 65) + nt * 16 + l15) * 8);
                acc[nt] = MFMA(a, b, acc[nt]);
            }
        }
        bf16x8 bfr[2];
        transpose_h(acc, bfr, l15, l4);

        f32x4 acc2[4];
#pragma unroll
        for (int nt = 0; nt < 4; ++nt) acc2[nt] = biasb[nt];
#pragma unroll
        for (int j = 0; j < 2; ++j) {
            const int c = j * 4 + l4;
#pragma unroll
            for (int nt = 0; nt < 4; ++nt) {
                bf16x8 a = *(const bf16x8*)(wfB + ((c * 65) + nt * 16 + l15) * 8);
                acc2[nt] = MFMA(a, bfr[j], acc2[nt]);
            }
        }
        if (node < N) {
#pragma unroll
            for (int nt = 0; nt < 4; ++nt) {
                f32x4 v;
#pragma unroll
                for (int r = 0; r < 4; ++r) v[r] = fmaxf(acc2[nt][r], 0.f);
                *(f32x4*)(out + (size_t)node * 64 + nt * 16 + l4 * 4) = v;
            }
        }
    }
}

// ---------------------------------------------------------------------------
// fallback node pass (f32 agg from device-atomic scatter)
// ---------------------------------------------------------------------------
__global__ __launch_bounds__(256) void node_pass_f32(
    const float* __restrict__ agg,
    const float* __restrict__ W2a, const float* __restrict__ W2b,
    const float* __restrict__ b2b,
    const float* __restrict__ y2, float* __restrict__ out,
    int N, int ntiles)
{
    __shared__ __align__(16) __bf16 wfA[8 * 65 * 8];
    __shared__ __align__(16) __bf16 wfB[8 * 65 * 8];
    for (int idx = threadIdx.x; idx < 64 * 64; idx += 256) {
        const int k = idx >> 6, n = idx & 63;
        const int c = k >> 3, i = k & 7;
        wfA[(c * 65 + n) * 8 + i] = (__bf16)W2a[(128 + k) * 64 + n];
        wfB[(c * 65 + n) * 8 + i] = (__bf16)W2b[k * 64 + n];
    }
    __syncthreads();

    const int lane = threadIdx.x & 63, wave = threadIdx.x >> 6;
    const int l15 = lane & 15, l4 = lane >> 4;

    f32x4 biasb[4];
#pragma unroll
    for (int nt = 0; nt < 4; ++nt) biasb[nt] = *(const f32x4*)(b2b + nt * 16 + l4 * 4);

    for (int tile = blockIdx.x * 4 + wave; tile < ntiles; tile += gridDim.x * 4) {
        const int node = tile * 16 + l15;
        const int nrow = min(node, N - 1);
        f32x4 acc[4];
#pragma unroll
        for (int nt = 0; nt < 4; ++nt)
            acc[nt] = *(const f32x4*)(y2 + (size_t)nrow * 64 + nt * 16 + l4 * 4);
#pragma unroll
        for (int j = 0; j < 2; ++j) {
            bf16x8 b = cvt8(agg + (size_t)nrow * 64 + j * 32 + l4 * 8);
            const int c = j * 4 + l4;
#pragma unroll
            for (int nt = 0; nt < 4; ++nt) {
                bf16x8 a = *(const bf16x8*)(wfA + ((c * 65) + nt * 16 + l15) * 8);
                acc[nt] = MFMA(a, b, acc[nt]);
            }
        }
        bf16x8 bfr[2];
        transpose_h(acc, bfr, l15, l4);
        f32x4 acc2[4];
#pragma unroll
        for (int nt = 0; nt < 4; ++nt) acc2[nt] = biasb[nt];
#pragma unroll
        for (int j = 0; j < 2; ++j) {
            const int c = j * 4 + l4;
#pragma unroll
            for (int nt = 0; nt < 4; ++nt) {
                bf16x8 a = *(const bf16x8*)(wfB + ((c * 65) + nt * 16 + l15) * 8);
                acc2[nt] = MFMA(a, bfr[j], acc2[nt]);
            }
        }
        if (node < N) {
#pragma unroll
            for (int nt = 0; nt < 4; ++nt) {
                f32x4 v;
#pragma unroll
                for (int r = 0; r < 4; ++r) v[r] = fmaxf(acc2[nt][r], 0.f);
                *(f32x4*)(out + (size_t)node * 64 + nt * 16 + l4 * 4) = v;
            }
        }
    }
}

// ---------------------------------------------------------------------------
extern "C" void kernel_launch(void* const* d_in, const int* in_sizes, int n_in,
                              void* d_out, int out_size, void* d_ws, size_t ws_size,
                              hipStream_t stream) {
    const float* x     = (const float*)d_in[0];
    const int*   eidx  = (const int*)d_in[1];
    const float* eattr = (const float*)d_in[2];
    // d_in[3] = u (unused), d_in[4] = batch (unused)
    const float* W1a = (const float*)d_in[5];
    const float* b1a = (const float*)d_in[6];
    const float* W1b = (const float*)d_in[7];
    const float* b1b = (const float*)d_in[8];
    const float* W2a = (const float*)d_in[9];
    const float* b2a = (const float*)d_in[10];
    const float* W2b = (const float*)d_in[11];
    const float* b2b = (const float*)d_in[12];
    float* out = (float*)d_out;

    const int N = in_sizes[0] / 128;
    const int E = in_sizes[1] / 2;
    const int* send = eidx;
    const int* recv = eidx + E;

    const size_t NG = (size_t)N * 64;
    const size_t need = NG * 2 + NG * 4 + (size_t)E * 64 * 2
                      + ((size_t)2 * (N + 1) + E) * sizeof(int);
    const bool big = ws_size >= need;

    const int ntilesN = (N + 15) / 16;
    const int ntilesE = (E + 15) / 16;
    int blkN = (ntilesN + 3) / 4;
    if (blkN > 1024) blkN = 1024;
    int blkE = (ntilesE + 3) / 4;
    if (blkE > 2048) blkE = 2048;   // 8 blocks/CU (16.6 KB LDS)
    int blkS = (E + 255) / 256;
    if (blkS > 1024) blkS = 1024;
    int blkF = (ntilesN + 3) / 4;
    if (blkF > 1536) blkF = 1536;

    if (big) {
        // layout: y1f(bf16) | y2(f32) | msgC(bf16) | cnt | offs | rank
        __bf16* y1f  = (__bf16*)d_ws;
        float*  y2   = (float*)(y1f + NG);
        __bf16* msgC = (__bf16*)(y2 + NG);
        int*    cnt  = (int*)(msgC + (size_t)E * 64);
        int*    offs = cnt + (N + 1);
        int*    rank = offs + (N + 1);

        zero_i32<<<(N + 256) / 256, 256, 0, stream>>>(cnt, N + 1);
        hist_rank<<<blkS, 256, 0, stream>>>(recv, cnt, rank, E);
        scan_offsets<<<1, 1024, 0, stream>>>(cnt, offs, N);
        precompute_y<<<blkN, 256, 0, stream>>>(x, W1a, b1a, W2a, b2a, y1f, y2, N, ntilesN);
        edge_mlp<0><<<blkE, 256, 0, stream>>>(eattr, send, recv, rank, offs,
                                              W1a, W1b, b1b, y1f, msgC, nullptr, E, ntilesE);
        node_fused<<<blkF, 256, 0, stream>>>((const unsigned*)msgC, offs,
                                             W2a, W2b, b2b, y2, out, N, ntilesN);
    } else {
        // fallback: agg(f32) | y1f(bf16) | y2(f32) with device-atomic scatter
        float*  agg = (float*)d_ws;
        __bf16* y1f = (__bf16*)(agg + NG);
        float*  y2  = (float*)(y1f + NG);
        zero_i32<<<2048, 256, 0, stream>>>((int*)agg, (int)NG);
        precompute_y<<<blkN, 256, 0, stream>>>(x, W1a, b1a, W2a, b2a, y1f, y2, N, ntilesN);
        edge_mlp<1><<<blkE, 256, 0, stream>>>(eattr, send, recv, nullptr, nullptr,
                                              W1a, W1b, b1b, y1f, nullptr, agg, E, ntilesE);
        node_pass_f32<<<blkN, 256, 0, stream>>>(agg, W2a, W2b, b2b, y2, out, N, ntilesN);
    }
}